// Round 3
// baseline (335.552 us; speedup 1.0000x reference)
//
#include <hip/hip_runtime.h>
#include <math.h>

#define BS   64
#define CH   256
#define NPIX 3136        // 56*56
#define NK   3

// ---- ws layout (floats) ----
#define WS_CSQ   0            // [4]  (3 used)
#define WS_RB    4            // [4]  rbeta = 1/sigmoid(psf)
#define WS_CTR4  8            // [CH][4]  {c0,c1,c2,0}
#define WS_SA    (8 + CH*4)   // [BS][NK]    = 1032
#define WS_QX    (WS_SA + BS*NK) // [BS][NK][CH]

// ---------------------------------------------------------------------------
// K0: one-wave setup — transpose centers to float4 ctr4[c], csq[k], rbeta[k].
// ---------------------------------------------------------------------------
__global__ __launch_bounds__(64)
void pgn_setup(const float* __restrict__ centers, const float* __restrict__ psf,
               float* __restrict__ ws)
{
    const int lane = threadIdx.x;   // 64 threads
    float4* ctr4 = (float4*)(ws + WS_CTR4);
    #pragma unroll
    for (int j = 0; j < 4; ++j) {
        const int c = lane * 4 + j;
        ctr4[c] = make_float4(centers[c], centers[CH + c], centers[2*CH + c], 0.f);
    }
    #pragma unroll
    for (int k = 0; k < NK; ++k) {
        float s = 0.f;
        #pragma unroll
        for (int j = 0; j < 4; ++j) {
            const float u = centers[k*CH + lane*4 + j];
            s = fmaf(u, u, s);
        }
        #pragma unroll
        for (int m = 32; m; m >>= 1) s += __shfl_xor(s, m, 64);
        if (lane == 0) ws[WS_CSQ + k] = s;
    }
    if (lane < NK) ws[WS_RB + lane] = 1.f + __expf(-psf[lane]);
}

// ---------------------------------------------------------------------------
// K1: per-pixel soft assignment. 1 pixel/thread, coalesced channel loop.
// Writes assign[b][k][n] and atomically accumulates sum_ass[b][k].
// ---------------------------------------------------------------------------
#define TILE1 256
#define NT1   13   // ceil(3136/256), last tile 64 px

__global__ __launch_bounds__(256)
void pgn_assign(const float* __restrict__ x,        // [BS][CH][NPIX]
                const float* __restrict__ ws,
                float* __restrict__ assign_out,     // [BS][NK][NPIX]
                float* __restrict__ sa)             // [BS][NK] (zeroed)
{
    __shared__ float4 ctr[CH];   // 4 KB broadcast copy
    const int tid = threadIdx.x;
    const int b   = blockIdx.x / NT1;
    const int t   = blockIdx.x % NT1;
    const int n   = t * TILE1 + tid;

    ctr[tid] = ((const float4*)(ws + WS_CTR4))[tid];
    __syncthreads();

    const float cs0 = ws[WS_CSQ+0], cs1 = ws[WS_CSQ+1], cs2 = ws[WS_CSQ+2];
    const float rb0 = ws[WS_RB+0],  rb1 = ws[WS_RB+1],  rb2 = ws[WS_RB+2];

    float a0 = 0.f, a1 = 0.f, a2 = 0.f;
    if (n < NPIX) {
        const float* xb = x + (size_t)b * CH * NPIX + n;
        float c0 = 0.f, c1 = 0.f, c2 = 0.f, xs = 0.f;
        #pragma unroll 8
        for (int c = 0; c < CH; ++c) {
            const float  xv = xb[(size_t)c * NPIX];
            const float4 cc = ctr[c];
            c0 = fmaf(cc.x, xv, c0);
            c1 = fmaf(cc.y, xv, c1);
            c2 = fmaf(cc.z, xv, c2);
            xs = fmaf(xv, xv, xs);
        }
        const float l0 = fminf(2.f*c0 - xs - cs0, 0.f) * rb0;
        const float l1 = fminf(2.f*c1 - xs - cs1, 0.f) * rb1;
        const float l2 = fminf(2.f*c2 - xs - cs2, 0.f) * rb2;
        const float m  = fmaxf(l0, fmaxf(l1, l2));
        const float e0 = __expf(l0 - m), e1 = __expf(l1 - m), e2 = __expf(l2 - m);
        const float inv = 1.f / (e0 + e1 + e2);
        a0 = e0 * inv; a1 = e1 * inv; a2 = e2 * inv;

        float* ao = assign_out + (size_t)b * NK * NPIX + n;
        ao[0]        = a0;
        ao[NPIX]     = a1;
        ao[2*NPIX]   = a2;
    }

    // wave-reduce the 3 assignment sums; one atomic per wave per k
    float s0 = a0, s1 = a1, s2 = a2;
    #pragma unroll
    for (int m = 32; m; m >>= 1) {
        s0 += __shfl_xor(s0, m, 64);
        s1 += __shfl_xor(s1, m, 64);
        s2 += __shfl_xor(s2, m, 64);
    }
    if ((tid & 63) == 0) {
        atomicAdd(&sa[b*NK + 0], s0);
        atomicAdd(&sa[b*NK + 1], s1);
        atomicAdd(&sa[b*NK + 2], s2);
    }
}

// ---------------------------------------------------------------------------
// K2: weighted pooling qx[b][k][c] = sum_n assign[b][k][n] * x[b][c][n].
// Block = (b, group of 8 channels); fully coalesced float4 reads; block
// reduction; exclusive writes (no atomics).
// ---------------------------------------------------------------------------
#define CPB 8            // channels per block
#define NCB (CH/CPB)     // 32 channel-blocks per image

__global__ __launch_bounds__(256)
void pgn_pool(const float* __restrict__ x,       // [BS][CH][NPIX]
              const float* __restrict__ assign,  // [BS][NK][NPIX]
              float* __restrict__ qx)            // [BS][NK][CH]
{
    const int tid = threadIdx.x;
    const int b   = blockIdx.x / NCB;
    const int c0  = (blockIdx.x % NCB) * CPB;

    const float* ab = assign + (size_t)b * NK * NPIX;
    const float* xb = x + ((size_t)b * CH + c0) * NPIX;

    float q[CPB][NK];
    #pragma unroll
    for (int j = 0; j < CPB; ++j)
        #pragma unroll
        for (int k = 0; k < NK; ++k) q[j][k] = 0.f;

    for (int p = tid * 4; p + 3 < NPIX; p += 256 * 4) {
        const float4 A0 = *(const float4*)(ab + p);
        const float4 A1 = *(const float4*)(ab + NPIX + p);
        const float4 A2 = *(const float4*)(ab + 2*NPIX + p);
        #pragma unroll
        for (int j = 0; j < CPB; ++j) {
            const float4 xv = *(const float4*)(xb + (size_t)j * NPIX + p);
            q[j][0] = fmaf(A0.x, xv.x, fmaf(A0.y, xv.y, fmaf(A0.z, xv.z, fmaf(A0.w, xv.w, q[j][0]))));
            q[j][1] = fmaf(A1.x, xv.x, fmaf(A1.y, xv.y, fmaf(A1.z, xv.z, fmaf(A1.w, xv.w, q[j][1]))));
            q[j][2] = fmaf(A2.x, xv.x, fmaf(A2.y, xv.y, fmaf(A2.z, xv.z, fmaf(A2.w, xv.w, q[j][2]))));
        }
    }

    // block-reduce 24 partials
    __shared__ float part[4][CPB*NK];
    const int wave = tid >> 6, lane = tid & 63;
    #pragma unroll
    for (int j = 0; j < CPB; ++j)
        #pragma unroll
        for (int k = 0; k < NK; ++k) {
            float v = q[j][k];
            #pragma unroll
            for (int m = 32; m; m >>= 1) v += __shfl_xor(v, m, 64);
            if (lane == 0) part[wave][j*NK + k] = v;
        }
    __syncthreads();
    if (tid < CPB*NK) {
        const float tot = part[0][tid] + part[1][tid] + part[2][tid] + part[3][tid];
        const int j = tid / NK, k = tid % NK;
        qx[((size_t)b*NK + k)*CH + c0 + j] = tot;
    }
}

// ---------------------------------------------------------------------------
// K3: finalize — qx/sum_ass, subtract centers, /sigma, L2-normalize over
// channels, transposed store to outputs[b][c][k].
// ---------------------------------------------------------------------------
__global__ __launch_bounds__(256)
void pgn_final(const float* __restrict__ ws,
               const float* __restrict__ centers,  // [NK][CH]
               const float* __restrict__ psf,      // [NK]
               float* __restrict__ out)            // [BS][CH][NK]
{
    const int b = blockIdx.x;
    const int c = threadIdx.x;
    const int wave = c >> 6, lane = c & 63;
    __shared__ float red[4][NK];
    __shared__ float nrm[NK];

    const float* qx = ws + WS_QX;
    const float* sa = ws + WS_SA;

    float v[NK], ss[NK];
    #pragma unroll
    for (int k = 0; k < NK; ++k) {
        const float beta = 1.f / (1.f + __expf(-psf[k]));
        const float sig  = sqrtf(0.5f * beta);
        const float s    = fmaxf(sa[b*NK + k], 1e-5f);
        const float q    = qx[((size_t)b*NK + k)*CH + c] / s;
        v[k]  = (q - centers[k*CH + c]) / sig;
        ss[k] = v[k] * v[k];
    }
    #pragma unroll
    for (int m = 32; m; m >>= 1) {
        ss[0] += __shfl_xor(ss[0], m, 64);
        ss[1] += __shfl_xor(ss[1], m, 64);
        ss[2] += __shfl_xor(ss[2], m, 64);
    }
    if (lane == 0) { red[wave][0] = ss[0]; red[wave][1] = ss[1]; red[wave][2] = ss[2]; }
    __syncthreads();
    if (c < NK) {
        const float tot = red[0][c] + red[1][c] + red[2][c] + red[3][c];
        nrm[c] = fmaxf(sqrtf(tot), 1e-12f);
    }
    __syncthreads();
    float* o = out + ((size_t)b*CH + c)*NK;
    #pragma unroll
    for (int k = 0; k < NK; ++k) o[k] = v[k] / nrm[k];
}

// ---------------------------------------------------------------------------
extern "C" void kernel_launch(void* const* d_in, const int* in_sizes, int n_in,
                              void* d_out, int out_size, void* d_ws, size_t ws_size,
                              hipStream_t stream)
{
    const float* feat    = (const float*)d_in[0];
    const float* centers = (const float*)d_in[1];
    const float* psf     = (const float*)d_in[2];

    float* out        = (float*)d_out;            // [BS][CH][NK] first
    float* assign_out = out + (size_t)BS*CH*NK;   // then [BS][NK][NPIX]

    float* ws = (float*)d_ws;
    float* sa = ws + WS_SA;
    float* qx = ws + WS_QX;

    // zero only the atomic accumulator (sa)
    hipMemsetAsync(sa, 0, BS*NK*sizeof(float), stream);

    pgn_setup<<<dim3(1), dim3(64), 0, stream>>>(centers, psf, ws);
    pgn_assign<<<dim3(BS*NT1), dim3(256), 0, stream>>>(feat, ws, assign_out, sa);
    pgn_pool<<<dim3(BS*NCB), dim3(256), 0, stream>>>(feat, assign_out, qx);
    pgn_final<<<dim3(BS), dim3(256), 0, stream>>>(ws, centers, psf, out);
}

// Round 4
// 299.316 us; speedup vs baseline: 1.1211x; 1.1211x over previous
//
#include <hip/hip_runtime.h>
#include <math.h>

#define BS   64
#define CH   256
#define NPIX 3136        // 56*56
#define NK   3
#define P    64          // pixels per block tile
#define NT   49          // 3136 / 64, exact
#define XPAD 68          // padded LDS row stride (floats): 68%4==0 (float4 ok), odd/32 spread

// ws layout (floats): sa then qx
#define WS_SA 0
#define WS_QX (BS*NK)

// ---------------------------------------------------------------------------
// Fused kernel: stage x tile to LDS once; phase A computes soft assignment
// from the load registers; phase B pools from LDS. x read from HBM exactly once.
// ---------------------------------------------------------------------------
__global__ __launch_bounds__(256)
void pgn_main(const float* __restrict__ x,        // [BS][CH][NPIX]
              const float* __restrict__ centers,  // [NK][CH]
              const float* __restrict__ psf,      // [NK]
              float* __restrict__ assign_out,     // [BS][NK][NPIX]
              float* __restrict__ sa,             // [BS][NK]      (zeroed)
              float* __restrict__ qx)             // [BS][NK][CH]  (zeroed)
{
    __shared__ float  x_sh[CH * XPAD];   // 69632 B
    __shared__ float4 ctr_sh[CH];        // 4096 B
    __shared__ float  part[4][16][16];   // 4096 B  phase-A partial dots
    __shared__ float  a_sh[NK][P];       // 768 B
    __shared__ float  cred[4][NK];       // csq wave partials
    __shared__ float  csq_sh[NK];

    const int tid  = threadIdx.x;
    const int b    = blockIdx.x / NT;
    const int t    = blockIdx.x % NT;
    const int n0   = t * P;
    const int pq   = tid & 15;    // pixel-quad index (pixels 4pq..4pq+3)
    const int cc   = tid >> 4;    // channel chunk (c = 16*i + cc)
    const int lane = tid & 63;
    const int w    = tid >> 6;

    // ---- centers transpose + c_sq (once per block, cheap) ----
    {
        const float c0 = centers[tid], c1 = centers[CH + tid], c2 = centers[2*CH + tid];
        ctr_sh[tid] = make_float4(c0, c1, c2, 0.f);
        float s0 = c0*c0, s1 = c1*c1, s2 = c2*c2;
        #pragma unroll
        for (int m = 32; m; m >>= 1) {
            s0 += __shfl_xor(s0, m, 64);
            s1 += __shfl_xor(s1, m, 64);
            s2 += __shfl_xor(s2, m, 64);
        }
        if (lane == 0) { cred[w][0] = s0; cred[w][1] = s1; cred[w][2] = s2; }
    }
    __syncthreads();
    if (tid < NK) csq_sh[tid] = cred[0][tid] + cred[1][tid] + cred[2][tid] + cred[3][tid];

    // ---- Phase A: load x tile (coalesced float4), stage to LDS, and
    //      accumulate partial center-dots from the load registers. ----
    float cxa[NK][4], xsq[4];
    #pragma unroll
    for (int j = 0; j < 4; ++j) { cxa[0][j]=0.f; cxa[1][j]=0.f; cxa[2][j]=0.f; xsq[j]=0.f; }

    const float* xb = x + (size_t)b * CH * NPIX + (n0 + 4*pq);
    #pragma unroll
    for (int i = 0; i < 16; ++i) {
        const int c = 16*i + cc;
        const float4 xv = *(const float4*)(xb + (size_t)c * NPIX);
        ((float4*)(x_sh + c * XPAD))[pq] = xv;
        const float4 cv = ctr_sh[c];
        const float xj[4] = {xv.x, xv.y, xv.z, xv.w};
        #pragma unroll
        for (int j = 0; j < 4; ++j) {
            cxa[0][j] = fmaf(cv.x, xj[j], cxa[0][j]);
            cxa[1][j] = fmaf(cv.y, xj[j], cxa[1][j]);
            cxa[2][j] = fmaf(cv.z, xj[j], cxa[2][j]);
            xsq[j]    = fmaf(xj[j], xj[j], xsq[j]);
        }
    }

    // reduce over the wave's 4 channel-chunks (lanes l, l^16, l^32, l^48)
    #pragma unroll
    for (int j = 0; j < 4; ++j) {
        #pragma unroll
        for (int k = 0; k < NK; ++k) {
            cxa[k][j] += __shfl_xor(cxa[k][j], 16, 64);
            cxa[k][j] += __shfl_xor(cxa[k][j], 32, 64);
        }
        xsq[j] += __shfl_xor(xsq[j], 16, 64);
        xsq[j] += __shfl_xor(xsq[j], 32, 64);
    }
    if ((tid & 48) == 0) {   // lanes 0..15 of each wave
        float* pp = &part[w][pq][0];
        #pragma unroll
        for (int j = 0; j < 4; ++j) {
            pp[j]      = cxa[0][j];
            pp[4 + j]  = cxa[1][j];
            pp[8 + j]  = cxa[2][j];
            pp[12 + j] = xsq[j];
        }
    }
    __syncthreads();   // part, x_sh, csq_sh ready

    // ---- softmax for the 64 pixels (wave 0) ----
    if (tid < P) {
        const int p = tid, q = p >> 2, r = p & 3;
        float cx0 = 0.f, cx1 = 0.f, cx2 = 0.f, xs = 0.f;
        #pragma unroll
        for (int ww = 0; ww < 4; ++ww) {
            cx0 += part[ww][q][r];
            cx1 += part[ww][q][4 + r];
            cx2 += part[ww][q][8 + r];
            xs  += part[ww][q][12 + r];
        }
        const float rb0 = 1.f + __expf(-psf[0]);
        const float rb1 = 1.f + __expf(-psf[1]);
        const float rb2 = 1.f + __expf(-psf[2]);
        const float l0 = fminf(2.f*cx0 - xs - csq_sh[0], 0.f) * rb0;
        const float l1 = fminf(2.f*cx1 - xs - csq_sh[1], 0.f) * rb1;
        const float l2 = fminf(2.f*cx2 - xs - csq_sh[2], 0.f) * rb2;
        const float m  = fmaxf(l0, fmaxf(l1, l2));
        const float e0 = __expf(l0 - m), e1 = __expf(l1 - m), e2 = __expf(l2 - m);
        const float inv = 1.f / (e0 + e1 + e2);
        const float a0 = e0*inv, a1 = e1*inv, a2 = e2*inv;

        a_sh[0][p] = a0; a_sh[1][p] = a1; a_sh[2][p] = a2;

        float* ao = assign_out + (size_t)b * NK * NPIX + n0 + p;
        ao[0]        = a0;
        ao[NPIX]     = a1;
        ao[2*NPIX]   = a2;

        float s0 = a0, s1 = a1, s2 = a2;
        #pragma unroll
        for (int m2 = 32; m2; m2 >>= 1) {
            s0 += __shfl_xor(s0, m2, 64);
            s1 += __shfl_xor(s1, m2, 64);
            s2 += __shfl_xor(s2, m2, 64);
        }
        if (tid == 0) {
            atomicAdd(&sa[b*NK + 0], s0);
            atomicAdd(&sa[b*NK + 1], s1);
            atomicAdd(&sa[b*NK + 2], s2);
        }
    }
    __syncthreads();   // a_sh ready

    // ---- Phase B: thread = channel; pool from LDS (2-way alias = free) ----
    float q0 = 0.f, q1 = 0.f, q2 = 0.f;
    const float4* xr = (const float4*)(x_sh + tid * XPAD);
    const float4* A0 = (const float4*)&a_sh[0][0];
    const float4* A1 = (const float4*)&a_sh[1][0];
    const float4* A2 = (const float4*)&a_sh[2][0];
    #pragma unroll
    for (int i = 0; i < 16; ++i) {
        const float4 xv  = xr[i];
        const float4 a0v = A0[i], a1v = A1[i], a2v = A2[i];
        q0 = fmaf(a0v.x, xv.x, fmaf(a0v.y, xv.y, fmaf(a0v.z, xv.z, fmaf(a0v.w, xv.w, q0))));
        q1 = fmaf(a1v.x, xv.x, fmaf(a1v.y, xv.y, fmaf(a1v.z, xv.z, fmaf(a1v.w, xv.w, q1))));
        q2 = fmaf(a2v.x, xv.x, fmaf(a2v.y, xv.y, fmaf(a2v.z, xv.z, fmaf(a2v.w, xv.w, q2))));
    }
    float* qb = qx + (size_t)b * NK * CH + tid;
    atomicAdd(qb,        q0);
    atomicAdd(qb + CH,   q1);
    atomicAdd(qb + 2*CH, q2);
}

// ---------------------------------------------------------------------------
// Finalize: qx/sum_ass, subtract centers, /sigma, L2-normalize over channels,
// transposed store to outputs[b][c][k].
// ---------------------------------------------------------------------------
__global__ __launch_bounds__(256)
void pgn_final(const float* __restrict__ qx,       // [BS][NK][CH]
               const float* __restrict__ sa,       // [BS][NK]
               const float* __restrict__ centers,  // [NK][CH]
               const float* __restrict__ psf,      // [NK]
               float* __restrict__ out)            // [BS][CH][NK]
{
    const int b = blockIdx.x;
    const int c = threadIdx.x;
    const int wave = c >> 6, lane = c & 63;
    __shared__ float red[4][NK];
    __shared__ float nrm[NK];

    float v[NK], ss[NK];
    #pragma unroll
    for (int k = 0; k < NK; ++k) {
        const float beta = 1.f / (1.f + __expf(-psf[k]));
        const float sig  = sqrtf(0.5f * beta);
        const float s    = fmaxf(sa[b*NK + k], 1e-5f);
        const float q    = qx[((size_t)b*NK + k)*CH + c] / s;
        v[k]  = (q - centers[k*CH + c]) / sig;
        ss[k] = v[k] * v[k];
    }
    #pragma unroll
    for (int m = 32; m; m >>= 1) {
        ss[0] += __shfl_xor(ss[0], m, 64);
        ss[1] += __shfl_xor(ss[1], m, 64);
        ss[2] += __shfl_xor(ss[2], m, 64);
    }
    if (lane == 0) { red[wave][0] = ss[0]; red[wave][1] = ss[1]; red[wave][2] = ss[2]; }
    __syncthreads();
    if (c < NK) {
        const float tot = red[0][c] + red[1][c] + red[2][c] + red[3][c];
        nrm[c] = fmaxf(sqrtf(tot), 1e-12f);
    }
    __syncthreads();
    float* o = out + ((size_t)b*CH + c)*NK;
    #pragma unroll
    for (int k = 0; k < NK; ++k) o[k] = v[k] / nrm[k];
}

// ---------------------------------------------------------------------------
extern "C" void kernel_launch(void* const* d_in, const int* in_sizes, int n_in,
                              void* d_out, int out_size, void* d_ws, size_t ws_size,
                              hipStream_t stream)
{
    const float* feat    = (const float*)d_in[0];
    const float* centers = (const float*)d_in[1];
    const float* psf     = (const float*)d_in[2];

    float* out        = (float*)d_out;            // [BS][CH][NK] first
    float* assign_out = out + (size_t)BS*CH*NK;   // then [BS][NK][NPIX]

    float* sa = (float*)d_ws + WS_SA;             // [BS][NK]
    float* qx = (float*)d_ws + WS_QX;             // [BS][NK][CH]

    // zero the atomic accumulators (ws is poisoned 0xAA before every launch)
    hipMemsetAsync(d_ws, 0, (BS*NK + BS*NK*CH) * sizeof(float), stream);

    pgn_main<<<dim3(BS*NT), dim3(256), 0, stream>>>(
        feat, centers, psf, assign_out, sa, qx);

    pgn_final<<<dim3(BS), dim3(256), 0, stream>>>(qx, sa, centers, psf, out);
}